// Round 5
// baseline (188.544 us; speedup 1.0000x reference)
//
#include <hip/hip_runtime.h>
#include <hip/hip_fp16.h>

typedef _Float16 f16;
typedef __attribute__((ext_vector_type(8))) _Float16 f16x8;
typedef __attribute__((ext_vector_type(4))) _Float16 f16x4;
typedef __attribute__((ext_vector_type(4))) float f32x4;

#define MFMA16(a, b, c) __builtin_amdgcn_mfma_f32_16x16x32_f16((a), (b), (c), 0, 0, 0)

// ---------------- workspace layout (bytes) ----------------
#define OFF_WK   0u              // w_k folded f16 [256][256]
#define OFF_WS   131072u         // w_s folded f16 [256][256]
#define OFF_WH1  262144u         // w_h1 folded f16 [256][256]
#define OFF_W2P  393216u         // w_h2 padded f16 [32][256]
#define OFF_SH   409600u         // shifts f32 [3][256]
#define OFF_S    412672u         // s feat f16 [123008][256]
#define OFF_KF   63392768u       // k feat f16 [6272][256]
#define OFF_FEAT 66604032u       // xcorr out f16 [80000][256]

// ---------------- weight prep: fold BN scale, convert to f16, pad W2 ----------------
__global__ __launch_bounds__(256) void prep_weights(
    const float* __restrict__ wk, const float* __restrict__ gk, const float* __restrict__ bk,
    const float* __restrict__ mk, const float* __restrict__ vk,
    const float* __restrict__ wsr, const float* __restrict__ gs, const float* __restrict__ bs,
    const float* __restrict__ ms, const float* __restrict__ vs,
    const float* __restrict__ wh1, const float* __restrict__ gh, const float* __restrict__ bh,
    const float* __restrict__ mh, const float* __restrict__ vh,
    const float* __restrict__ wh2,
    f16* __restrict__ wk16, f16* __restrict__ ws16, f16* __restrict__ wh116,
    f16* __restrict__ w2p, float* __restrict__ shifts) {
  int o = blockIdx.x;
  int t = threadIdx.x;
  float sck = gk[o] * rsqrtf(vk[o] + 1e-5f);
  float scs = gs[o] * rsqrtf(vs[o] + 1e-5f);
  float sch = gh[o] * rsqrtf(vh[o] + 1e-5f);
  int idx = o * 256 + t;
  wk16[idx]  = (f16)(wk[idx] * sck);
  ws16[idx]  = (f16)(wsr[idx] * scs);
  wh116[idx] = (f16)(wh1[idx] * sch);
  if (o < 32) w2p[idx] = (o < 20) ? (f16)wh2[idx] : (f16)0;
  if (t == 0) {
    shifts[o]       = bk[o] - mk[o] * sck;
    shifts[256 + o] = bs[o] - ms[o] * scs;
    shifts[512 + o] = bh[o] - mh[o] * sch;
  }
}

// ---------------- conv1x1+BN+ReLU, fp32 NCHW -> f16 [N][256], all 256 outputs per block ----
// Stage: lanes 0-15 read 16 consecutive float4 (256B runs); reg 4x4 transpose;
// XOR-swizzled LDS 16B blocks: byte(c,n) = (c>>3)*1024 + (n^((n>>3)&7))*16 + (c&7)*2.
// Output: C-frags -> swizzled LDS (reused) -> 128B-contiguous per-thread global stores.
template <int P>
__global__ __launch_bounds__(256, 4) void conv_f32_allo(
    const float* __restrict__ X, const f16* __restrict__ W,
    const float* __restrict__ shift, f16* __restrict__ out) {
  const int C = 256;
  const int CP = C * P;
  int n0 = blockIdx.x * 64;
  int t = threadIdx.x;
  int lane = t & 63, wave = t >> 6;
  int fm = lane & 15, kg = lane >> 4;

  __shared__ char bs[32768];   // 64n x 256c f16, swizzled

  // ---- stage ----
  {
    int px0 = (t & 15) * 4;         // 4 consecutive pixels
    int cq  = (t >> 4) * 4;         // channel quad base within each 64-chunk
    int gn0 = n0 + px0;
    int bq = gn0 / P, bp = gn0 - bq * P;
    const float* xb = X + (size_t)bq * CP + bp;
    bool safe = (bp + 3 < P);
#pragma unroll
    for (int j = 0; j < 4; ++j) {
      int cb = j * 64 + cq;
      f32x4 col[4];                 // col[i][e] = X[cb+i][gn0+e]
      if (safe) {
#pragma unroll
        for (int i = 0; i < 4; ++i) col[i] = *(const f32x4*)(xb + (size_t)(cb + i) * P);
      } else {
#pragma unroll
        for (int i = 0; i < 4; ++i)
#pragma unroll
          for (int e = 0; e < 4; ++e) {
            int gn = gn0 + e;
            int bqe = gn / P, bpe = gn - bqe * P;
            col[i][e] = X[(size_t)bqe * CP + (size_t)(cb + i) * P + bpe];
          }
      }
#pragma unroll
      for (int e = 0; e < 4; ++e) {
        int ne = px0 + e;
        f16x4 v;
        v[0] = (f16)col[0][e]; v[1] = (f16)col[1][e];
        v[2] = (f16)col[2][e]; v[3] = (f16)col[3][e];
        *(f16x4*)(bs + ((cb >> 3) << 10) + ((ne ^ ((ne >> 3) & 7)) << 4) + ((cb & 7) << 1)) = v;
      }
    }
  }
  __syncthreads();

  const f16* wp = W + (size_t)(wave * 64 + fm) * C + kg * 8;
  int nsw[4];
#pragma unroll
  for (int nf = 0; nf < 4; ++nf) {
    int n = nf * 16 + fm;
    nsw[nf] = (n ^ ((n >> 3) & 7)) << 4;
  }

  f32x4 acc[4][4] = {};
#pragma unroll
  for (int ci = 0; ci < 8; ++ci) {      // c0 = ci*32
    f16x8 a[4], b[4];
#pragma unroll
    for (int of = 0; of < 4; ++of)
      a[of] = *(const f16x8*)(wp + (size_t)of * 16 * C + ci * 32);
#pragma unroll
    for (int nf = 0; nf < 4; ++nf)
      b[nf] = *(const f16x8*)(bs + ((ci * 4 + kg) << 10) + nsw[nf]);
#pragma unroll
    for (int of = 0; of < 4; ++of)
#pragma unroll
      for (int nf = 0; nf < 4; ++nf)
        acc[of][nf] = MFMA16(a[of], b[nf], acc[of][nf]);
  }
  __syncthreads();                       // bs about to be reused for C-tile

  // ---- shift+relu, C-frags -> swizzled LDS ----
#pragma unroll
  for (int of = 0; of < 4; ++of) {
    int orow = wave * 64 + of * 16 + kg * 4;
#pragma unroll
    for (int nf = 0; nf < 4; ++nf) {
      f16x4 st;
#pragma unroll
      for (int r = 0; r < 4; ++r)
        st[r] = (f16)fmaxf(acc[of][nf][r] + shift[orow + r], 0.0f);
      *(f16x4*)(bs + ((orow >> 3) << 10) + nsw[nf] + ((orow & 7) << 1)) = st;
    }
  }
  __syncthreads();

  // ---- coalesced global write: thread -> (row n = t>>2, o-chunk og = (t&3)*64) ----
  {
    int n = t >> 2;
    int og = (t & 3) * 64;
    f16* op = out + (size_t)(n0 + n) * 256 + og;
    int swn = (n ^ ((n >> 3) & 7)) << 4;
#pragma unroll
    for (int k = 0; k < 8; ++k) {
      f16x8 v = *(const f16x8*)(bs + (((og >> 3) + k) << 10) + swn);
      *(f16x8*)(op + k * 8) = v;
    }
  }
}

// ---------------- depthwise xcorr, row-per-wave with register reuse ----------------
__global__ __launch_bounds__(256) void xcorr_dw_row(
    const f16* __restrict__ S /* [128][31][31][256] */,
    const f16* __restrict__ K /* [128][7][7][256] */,
    f16* __restrict__ F /* [128][25][25][256] */) {
  int id = blockIdx.x;            // 0..895, XCD-swizzled
  int x = id & 7;
  int r = id >> 3;
  int g = r % 7;
  int bq = r / 7;
  int b = bq * 8 + x;

  int wave = threadIdx.x >> 6;
  int lane = threadIdx.x & 63;
  int oi = g * 4 + wave;          // 0..27
  if (oi >= 25) return;

  const f16* Sb = S + (size_t)b * 961 * 256 + lane * 4;
  const f16* Kb = K + (size_t)b * 49 * 256 + lane * 4;

  f32x4 acc[25] = {};

  for (int di = 0; di < 7; ++di) {
    const f16* sp = Sb + (size_t)(oi + di) * 31 * 256;
    f16x4 srow[31];
#pragma unroll
    for (int j = 0; j < 31; ++j) srow[j] = *(const f16x4*)(sp + (size_t)j * 256);
    const f16* kp = Kb + (size_t)di * 7 * 256;
    f16x4 krow[7];
#pragma unroll
    for (int j = 0; j < 7; ++j) krow[j] = *(const f16x4*)(kp + (size_t)j * 256);

#pragma unroll
    for (int dj = 0; dj < 7; ++dj) {
      float k0 = (float)krow[dj][0];
      float k1 = (float)krow[dj][1];
      float k2 = (float)krow[dj][2];
      float k3 = (float)krow[dj][3];
#pragma unroll
      for (int oj = 0; oj < 25; ++oj) {
        f16x4 sv = srow[oj + dj];
        acc[oj][0] += (float)sv[0] * k0;
        acc[oj][1] += (float)sv[1] * k1;
        acc[oj][2] += (float)sv[2] * k2;
        acc[oj][3] += (float)sv[3] * k3;
      }
    }
  }

  f16* Fb = F + ((size_t)b * 625 + (size_t)oi * 25) * 256 + lane * 4;
#pragma unroll
  for (int oj = 0; oj < 25; ++oj) {
    f16x4 o;
#pragma unroll
    for (int e = 0; e < 4; ++e) o[e] = (f16)acc[oj][e];
    *(f16x4*)(Fb + (size_t)oj * 256) = o;
  }
}

// ---------------- fused head: conv1(256->256)+BN+ReLU then conv2(256->20)+bias ----------
__global__ __launch_bounds__(256) void head_fused(
    const f16* __restrict__ Xt /* feat [80000][256] */,
    const f16* __restrict__ W1, const float* __restrict__ shift,
    const f16* __restrict__ W2p /* [32][256] */, const float* __restrict__ bias,
    float* __restrict__ out /* [128][20][625] */) {
  const int C = 256;
  int n0 = blockIdx.x * 64;
  int t = threadIdx.x;
  int lane = t & 63, wave = t >> 6;
  int fm = lane & 15, kg = lane >> 4;

  __shared__ f16 Ys[32][64][8];   // y-tile chunk-major

  const f16* wp = W1 + (size_t)(wave * 64 + fm) * C + kg * 8;
  const f16* xp = Xt + (size_t)(n0 + fm) * C + kg * 8;

  f32x4 acc[4][4] = {};
#pragma unroll
  for (int c0 = 0; c0 < 256; c0 += 32) {
    f16x8 a[4], b[4];
#pragma unroll
    for (int of = 0; of < 4; ++of) a[of] = *(const f16x8*)(wp + (size_t)of * 16 * C + c0);
#pragma unroll
    for (int nf = 0; nf < 4; ++nf) b[nf] = *(const f16x8*)(xp + (size_t)nf * 16 * C + c0);
#pragma unroll
    for (int of = 0; of < 4; ++of)
#pragma unroll
      for (int nf = 0; nf < 4; ++nf)
        acc[of][nf] = MFMA16(a[of], b[nf], acc[of][nf]);
  }

#pragma unroll
  for (int of = 0; of < 4; ++of) {
    int orow = wave * 64 + of * 16 + kg * 4;
#pragma unroll
    for (int nf = 0; nf < 4; ++nf) {
      int n = nf * 16 + fm;
      f16x4 st;
#pragma unroll
      for (int r = 0; r < 4; ++r)
        st[r] = (f16)fmaxf(acc[of][nf][r] + shift[orow + r], 0.0f);
      *(f16x4*)&Ys[orow >> 3][n][(kg & 1) * 4] = st;
    }
  }
  __syncthreads();

  // GEMM2: M=32 (20 live), N=64 (wave -> 16 n), K=256
  f32x4 acc2[2] = {};
#pragma unroll
  for (int c0 = 0; c0 < 256; c0 += 32) {
    f16x8 b = *(const f16x8*)&Ys[(c0 >> 3) + kg][wave * 16 + fm][0];
    f16x8 a0 = *(const f16x8*)(W2p + (size_t)fm * C + c0 + kg * 8);
    f16x8 a1 = *(const f16x8*)(W2p + (size_t)(16 + fm) * C + c0 + kg * 8);
    acc2[0] = MFMA16(a0, b, acc2[0]);
    acc2[1] = MFMA16(a1, b, acc2[1]);
  }

  int n = n0 + wave * 16 + fm;
  int bq = n / 625, bp = n - bq * 625;
  float* op = out + (size_t)bq * 12500 + bp;
#pragma unroll
  for (int of = 0; of < 2; ++of) {
#pragma unroll
    for (int r = 0; r < 4; ++r) {
      int o = of * 16 + kg * 4 + r;
      if (o < 20) op[(size_t)o * 625] = acc2[of][r] + bias[o];
    }
  }
}

extern "C" void kernel_launch(void* const* d_in, const int* in_sizes, int n_in,
                              void* d_out, int out_size, void* d_ws, size_t ws_size,
                              hipStream_t stream) {
  const float* kernel_in = (const float*)d_in[0];
  const float* search    = (const float*)d_in[1];
  const float* w_k = (const float*)d_in[2];
  const float* g_k = (const float*)d_in[3];
  const float* b_k = (const float*)d_in[4];
  const float* m_k = (const float*)d_in[5];
  const float* v_k = (const float*)d_in[6];
  const float* w_s = (const float*)d_in[7];
  const float* g_s = (const float*)d_in[8];
  const float* b_s = (const float*)d_in[9];
  const float* m_s = (const float*)d_in[10];
  const float* v_s = (const float*)d_in[11];
  const float* w_h1 = (const float*)d_in[12];
  const float* g_h = (const float*)d_in[13];
  const float* b_h = (const float*)d_in[14];
  const float* m_h = (const float*)d_in[15];
  const float* v_h = (const float*)d_in[16];
  const float* w_h2 = (const float*)d_in[17];
  const float* bias_h2 = (const float*)d_in[18];
  float* out = (float*)d_out;

  char* ws = (char*)d_ws;
  f16* wk16  = (f16*)(ws + OFF_WK);
  f16* ws16  = (f16*)(ws + OFF_WS);
  f16* wh116 = (f16*)(ws + OFF_WH1);
  f16* w2p   = (f16*)(ws + OFF_W2P);
  float* shifts = (float*)(ws + OFF_SH);
  f16* sbuf = (f16*)(ws + OFF_S);
  f16* kbuf = (f16*)(ws + OFF_KF);
  f16* fbuf = (f16*)(ws + OFF_FEAT);

  prep_weights<<<256, 256, 0, stream>>>(w_k, g_k, b_k, m_k, v_k,
                                        w_s, g_s, b_s, m_s, v_s,
                                        w_h1, g_h, b_h, m_h, v_h, w_h2,
                                        wk16, ws16, wh116, w2p, shifts);

  // search branch: 1922 n-tiles, each block does all 256 outputs
  conv_f32_allo<961><<<dim3(1922), 256, 0, stream>>>(
      search, ws16, shifts + 256, sbuf);

  // kernel branch: 98 n-tiles
  conv_f32_allo<49><<<dim3(98), 256, 0, stream>>>(
      kernel_in, wk16, shifts + 0, kbuf);

  // depthwise xcorr
  xcorr_dw_row<<<dim3(896), 256, 0, stream>>>(sbuf, kbuf, fbuf);

  // fused head: conv1+BN+ReLU+conv2+bias -> fp32 NCHW
  head_fused<<<dim3(1250), 256, 0, stream>>>(
      fbuf, wh116, shifts + 512, w2p, bias_h2, out);
}

// Round 6
// 179.591 us; speedup vs baseline: 1.0498x; 1.0498x over previous
//
#include <hip/hip_runtime.h>
#include <hip/hip_fp16.h>

typedef _Float16 f16;
typedef __attribute__((ext_vector_type(8))) _Float16 f16x8;
typedef __attribute__((ext_vector_type(4))) _Float16 f16x4;
typedef __attribute__((ext_vector_type(4))) float f32x4;

#define MFMA16(a, b, c) __builtin_amdgcn_mfma_f32_16x16x32_f16((a), (b), (c), 0, 0, 0)

// ---------------- workspace layout (bytes) ----------------
#define OFF_WK   0u              // w_k folded f16 [256][256]
#define OFF_WS   131072u         // w_s folded f16 [256][256]
#define OFF_WH1  262144u         // w_h1 folded f16 [256][256]
#define OFF_W2P  393216u         // w_h2 padded f16 [32][256]
#define OFF_SH   409600u         // shifts f32 [3][256]
#define OFF_S    412672u         // s feat f16 [123008][256]
#define OFF_KF   63392768u       // k feat f16 [6272][256]
#define OFF_FEAT 66604032u       // xcorr out f16 [80000][256]

// ---------------- weight prep: fold BN scale, convert to f16, pad W2 ----------------
__global__ __launch_bounds__(256) void prep_weights(
    const float* __restrict__ wk, const float* __restrict__ gk, const float* __restrict__ bk,
    const float* __restrict__ mk, const float* __restrict__ vk,
    const float* __restrict__ wsr, const float* __restrict__ gs, const float* __restrict__ bs,
    const float* __restrict__ ms, const float* __restrict__ vs,
    const float* __restrict__ wh1, const float* __restrict__ gh, const float* __restrict__ bh,
    const float* __restrict__ mh, const float* __restrict__ vh,
    const float* __restrict__ wh2,
    f16* __restrict__ wk16, f16* __restrict__ ws16, f16* __restrict__ wh116,
    f16* __restrict__ w2p, float* __restrict__ shifts) {
  int o = blockIdx.x;
  int t = threadIdx.x;
  float sck = gk[o] * rsqrtf(vk[o] + 1e-5f);
  float scs = gs[o] * rsqrtf(vs[o] + 1e-5f);
  float sch = gh[o] * rsqrtf(vh[o] + 1e-5f);
  int idx = o * 256 + t;
  wk16[idx]  = (f16)(wk[idx] * sck);
  ws16[idx]  = (f16)(wsr[idx] * scs);
  wh116[idx] = (f16)(wh1[idx] * sch);
  if (o < 32) w2p[idx] = (o < 20) ? (f16)wh2[idx] : (f16)0;
  if (t == 0) {
    shifts[o]       = bk[o] - mk[o] * sck;
    shifts[256 + o] = bs[o] - ms[o] * scs;
    shifts[512 + o] = bh[o] - mh[o] * sch;
  }
}

// ---------------- conv1x1+BN+ReLU, fp32 NCHW -> f16 [N][256], all 256 outputs per block ----
// Latency fix (R6): __launch_bounds__(256,2) -> 256-VGPR budget;
//  * wave's full weight panel (32 x f16x8 = 128 VGPR) hoisted to registers ONCE;
//  * all 16 stage float4 loads issued before any wait (64 VGPR of destinations);
//  * K-loop is pure ds_read_b128 + MFMA (no global access).
template <int P>
__global__ __launch_bounds__(256, 2) void conv_f32_allo(
    const float* __restrict__ X, const f16* __restrict__ W,
    const float* __restrict__ shift, f16* __restrict__ out) {
  const int C = 256;
  const int CP = C * P;
  int n0 = blockIdx.x * 64;
  int t = threadIdx.x;
  int lane = t & 63, wave = t >> 6;
  int fm = lane & 15, kg = lane >> 4;

  __shared__ char bs[32768];   // 64n x 256c f16, swizzled

  // ---- issue all 16 stage loads (lanes 0-15 form 256B contiguous runs) ----
  int px0 = (t & 15) * 4;         // 4 consecutive pixels
  int cq  = (t >> 4) * 4;         // channel quad base within each 64-chunk
  int gn0 = n0 + px0;
  int bq = gn0 / P, bp = gn0 - bq * P;
  const float* xb = X + (size_t)bq * CP + bp;
  bool safe = (bp + 3 < P);
  f32x4 col[4][4];                // col[j][i][e] = X[j*64+cq+i][gn0+e]
  if (safe) {
#pragma unroll
    for (int j = 0; j < 4; ++j)
#pragma unroll
      for (int i = 0; i < 4; ++i)
        col[j][i] = *(const f32x4*)(xb + (size_t)(j * 64 + cq + i) * P);
  } else {
#pragma unroll
    for (int j = 0; j < 4; ++j)
#pragma unroll
      for (int i = 0; i < 4; ++i)
#pragma unroll
        for (int e = 0; e < 4; ++e) {
          int gn = gn0 + e;
          int bqe = gn / P, bpe = gn - bqe * P;
          col[j][i][e] = X[(size_t)bqe * CP + (size_t)(j * 64 + cq + i) * P + bpe];
        }
  }

  // ---- hoist the wave's weight panel into registers (L2-resident source) ----
  const f16* wp = W + (size_t)(wave * 64 + fm) * C + kg * 8;
  f16x8 a[8][4];                  // [ci][of], 128 VGPR
#pragma unroll
  for (int ci = 0; ci < 8; ++ci)
#pragma unroll
    for (int of = 0; of < 4; ++of)
      a[ci][of] = *(const f16x8*)(wp + (size_t)of * 16 * C + ci * 32);

  // ---- transpose + swizzled LDS write ----
#pragma unroll
  for (int j = 0; j < 4; ++j) {
    int cb = j * 64 + cq;
#pragma unroll
    for (int e = 0; e < 4; ++e) {
      int ne = px0 + e;
      f16x4 v;
      v[0] = (f16)col[j][0][e]; v[1] = (f16)col[j][1][e];
      v[2] = (f16)col[j][2][e]; v[3] = (f16)col[j][3][e];
      *(f16x4*)(bs + ((cb >> 3) << 10) + ((ne ^ ((ne >> 3) & 7)) << 4) + ((cb & 7) << 1)) = v;
    }
  }
  __syncthreads();

  int nsw[4];
#pragma unroll
  for (int nf = 0; nf < 4; ++nf) {
    int n = nf * 16 + fm;
    nsw[nf] = (n ^ ((n >> 3) & 7)) << 4;
  }

  // ---- pure LDS + MFMA K-loop ----
  f32x4 acc[4][4] = {};
#pragma unroll
  for (int ci = 0; ci < 8; ++ci) {
    f16x8 b[4];
#pragma unroll
    for (int nf = 0; nf < 4; ++nf)
      b[nf] = *(const f16x8*)(bs + ((ci * 4 + kg) << 10) + nsw[nf]);
#pragma unroll
    for (int of = 0; of < 4; ++of)
#pragma unroll
      for (int nf = 0; nf < 4; ++nf)
        acc[of][nf] = MFMA16(a[ci][of], b[nf], acc[of][nf]);
  }
  __syncthreads();                       // bs about to be reused for C-tile

  // ---- shift+relu, C-frags -> swizzled LDS ----
#pragma unroll
  for (int of = 0; of < 4; ++of) {
    int orow = wave * 64 + of * 16 + kg * 4;
#pragma unroll
    for (int nf = 0; nf < 4; ++nf) {
      f16x4 st;
#pragma unroll
      for (int r = 0; r < 4; ++r)
        st[r] = (f16)fmaxf(acc[of][nf][r] + shift[orow + r], 0.0f);
      *(f16x4*)(bs + ((orow >> 3) << 10) + nsw[nf] + ((orow & 7) << 1)) = st;
    }
  }
  __syncthreads();

  // ---- coalesced global write: thread -> (row n = t>>2, o-chunk og = (t&3)*64) ----
  {
    int n = t >> 2;
    int og = (t & 3) * 64;
    f16* op = out + (size_t)(n0 + n) * 256 + og;
    int swn = (n ^ ((n >> 3) & 7)) << 4;
#pragma unroll
    for (int k = 0; k < 8; ++k) {
      f16x8 v = *(const f16x8*)(bs + (((og >> 3) + k) << 10) + swn);
      *(f16x8*)(op + k * 8) = v;
    }
  }
}

// ---------------- depthwise xcorr, row-per-wave with register reuse ----------------
__global__ __launch_bounds__(256) void xcorr_dw_row(
    const f16* __restrict__ S /* [128][31][31][256] */,
    const f16* __restrict__ K /* [128][7][7][256] */,
    f16* __restrict__ F /* [128][25][25][256] */) {
  int id = blockIdx.x;            // 0..895, XCD-swizzled
  int x = id & 7;
  int r = id >> 3;
  int g = r % 7;
  int bq = r / 7;
  int b = bq * 8 + x;

  int wave = threadIdx.x >> 6;
  int lane = threadIdx.x & 63;
  int oi = g * 4 + wave;          // 0..27
  if (oi >= 25) return;

  const f16* Sb = S + (size_t)b * 961 * 256 + lane * 4;
  const f16* Kb = K + (size_t)b * 49 * 256 + lane * 4;

  f32x4 acc[25] = {};

  for (int di = 0; di < 7; ++di) {
    const f16* sp = Sb + (size_t)(oi + di) * 31 * 256;
    f16x4 srow[31];
#pragma unroll
    for (int j = 0; j < 31; ++j) srow[j] = *(const f16x4*)(sp + (size_t)j * 256);
    const f16* kp = Kb + (size_t)di * 7 * 256;
    f16x4 krow[7];
#pragma unroll
    for (int j = 0; j < 7; ++j) krow[j] = *(const f16x4*)(kp + (size_t)j * 256);

#pragma unroll
    for (int dj = 0; dj < 7; ++dj) {
      float k0 = (float)krow[dj][0];
      float k1 = (float)krow[dj][1];
      float k2 = (float)krow[dj][2];
      float k3 = (float)krow[dj][3];
#pragma unroll
      for (int oj = 0; oj < 25; ++oj) {
        f16x4 sv = srow[oj + dj];
        acc[oj][0] += (float)sv[0] * k0;
        acc[oj][1] += (float)sv[1] * k1;
        acc[oj][2] += (float)sv[2] * k2;
        acc[oj][3] += (float)sv[3] * k3;
      }
    }
  }

  f16* Fb = F + ((size_t)b * 625 + (size_t)oi * 25) * 256 + lane * 4;
#pragma unroll
  for (int oj = 0; oj < 25; ++oj) {
    f16x4 o;
#pragma unroll
    for (int e = 0; e < 4; ++e) o[e] = (f16)acc[oj][e];
    *(f16x4*)(Fb + (size_t)oj * 256) = o;
  }
}

// ---------------- fused head: conv1(256->256)+BN+ReLU then conv2(256->20)+bias ----------
__global__ __launch_bounds__(256) void head_fused(
    const f16* __restrict__ Xt /* feat [80000][256] */,
    const f16* __restrict__ W1, const float* __restrict__ shift,
    const f16* __restrict__ W2p /* [32][256] */, const float* __restrict__ bias,
    float* __restrict__ out /* [128][20][625] */) {
  const int C = 256;
  int n0 = blockIdx.x * 64;
  int t = threadIdx.x;
  int lane = t & 63, wave = t >> 6;
  int fm = lane & 15, kg = lane >> 4;

  __shared__ f16 Ys[32][64][8];   // y-tile chunk-major

  const f16* wp = W1 + (size_t)(wave * 64 + fm) * C + kg * 8;
  const f16* xp = Xt + (size_t)(n0 + fm) * C + kg * 8;

  f32x4 acc[4][4] = {};
#pragma unroll
  for (int c0 = 0; c0 < 256; c0 += 32) {
    f16x8 a[4], b[4];
#pragma unroll
    for (int of = 0; of < 4; ++of) a[of] = *(const f16x8*)(wp + (size_t)of * 16 * C + c0);
#pragma unroll
    for (int nf = 0; nf < 4; ++nf) b[nf] = *(const f16x8*)(xp + (size_t)nf * 16 * C + c0);
#pragma unroll
    for (int of = 0; of < 4; ++of)
#pragma unroll
      for (int nf = 0; nf < 4; ++nf)
        acc[of][nf] = MFMA16(a[of], b[nf], acc[of][nf]);
  }

#pragma unroll
  for (int of = 0; of < 4; ++of) {
    int orow = wave * 64 + of * 16 + kg * 4;
#pragma unroll
    for (int nf = 0; nf < 4; ++nf) {
      int n = nf * 16 + fm;
      f16x4 st;
#pragma unroll
      for (int r = 0; r < 4; ++r)
        st[r] = (f16)fmaxf(acc[of][nf][r] + shift[orow + r], 0.0f);
      *(f16x4*)&Ys[orow >> 3][n][(kg & 1) * 4] = st;
    }
  }
  __syncthreads();

  // GEMM2: M=32 (20 live), N=64 (wave -> 16 n), K=256
  f32x4 acc2[2] = {};
#pragma unroll
  for (int c0 = 0; c0 < 256; c0 += 32) {
    f16x8 b = *(const f16x8*)&Ys[(c0 >> 3) + kg][wave * 16 + fm][0];
    f16x8 a0 = *(const f16x8*)(W2p + (size_t)fm * C + c0 + kg * 8);
    f16x8 a1 = *(const f16x8*)(W2p + (size_t)(16 + fm) * C + c0 + kg * 8);
    acc2[0] = MFMA16(a0, b, acc2[0]);
    acc2[1] = MFMA16(a1, b, acc2[1]);
  }

  int n = n0 + wave * 16 + fm;
  int bq = n / 625, bp = n - bq * 625;
  float* op = out + (size_t)bq * 12500 + bp;
#pragma unroll
  for (int of = 0; of < 2; ++of) {
#pragma unroll
    for (int r = 0; r < 4; ++r) {
      int o = of * 16 + kg * 4 + r;
      if (o < 20) op[(size_t)o * 625] = acc2[of][r] + bias[o];
    }
  }
}

extern "C" void kernel_launch(void* const* d_in, const int* in_sizes, int n_in,
                              void* d_out, int out_size, void* d_ws, size_t ws_size,
                              hipStream_t stream) {
  const float* kernel_in = (const float*)d_in[0];
  const float* search    = (const float*)d_in[1];
  const float* w_k = (const float*)d_in[2];
  const float* g_k = (const float*)d_in[3];
  const float* b_k = (const float*)d_in[4];
  const float* m_k = (const float*)d_in[5];
  const float* v_k = (const float*)d_in[6];
  const float* w_s = (const float*)d_in[7];
  const float* g_s = (const float*)d_in[8];
  const float* b_s = (const float*)d_in[9];
  const float* m_s = (const float*)d_in[10];
  const float* v_s = (const float*)d_in[11];
  const float* w_h1 = (const float*)d_in[12];
  const float* g_h = (const float*)d_in[13];
  const float* b_h = (const float*)d_in[14];
  const float* m_h = (const float*)d_in[15];
  const float* v_h = (const float*)d_in[16];
  const float* w_h2 = (const float*)d_in[17];
  const float* bias_h2 = (const float*)d_in[18];
  float* out = (float*)d_out;

  char* ws = (char*)d_ws;
  f16* wk16  = (f16*)(ws + OFF_WK);
  f16* ws16  = (f16*)(ws + OFF_WS);
  f16* wh116 = (f16*)(ws + OFF_WH1);
  f16* w2p   = (f16*)(ws + OFF_W2P);
  float* shifts = (float*)(ws + OFF_SH);
  f16* sbuf = (f16*)(ws + OFF_S);
  f16* kbuf = (f16*)(ws + OFF_KF);
  f16* fbuf = (f16*)(ws + OFF_FEAT);

  prep_weights<<<256, 256, 0, stream>>>(w_k, g_k, b_k, m_k, v_k,
                                        w_s, g_s, b_s, m_s, v_s,
                                        w_h1, g_h, b_h, m_h, v_h, w_h2,
                                        wk16, ws16, wh116, w2p, shifts);

  // search branch: 1922 n-tiles, each block does all 256 outputs
  conv_f32_allo<961><<<dim3(1922), 256, 0, stream>>>(
      search, ws16, shifts + 256, sbuf);

  // kernel branch: 98 n-tiles
  conv_f32_allo<49><<<dim3(98), 256, 0, stream>>>(
      kernel_in, wk16, shifts + 0, kbuf);

  // depthwise xcorr
  xcorr_dw_row<<<dim3(896), 256, 0, stream>>>(sbuf, kbuf, fbuf);

  // fused head: conv1+BN+ReLU+conv2+bias -> fp32 NCHW
  head_fused<<<dim3(1250), 256, 0, stream>>>(
      fbuf, wh116, shifts + 512, w2p, bias_h2, out);
}